// Round 4
// baseline (1108.404 us; speedup 1.0000x reference)
//
#include <hip/hip_runtime.h>
#include <hip/hip_bf16.h>
#include <stdint.h>

#define N_NODES 2048
#define N_EDGES 32768
#define F_IN    50176
#define F_H     1024
#define F_H2    256
#define FSK1    8   // split-K layer1, fast path
#define FBK1    2   // split-K layer1, fallback path
#define SK2     8   // split-K layer2

using f32x4 = __attribute__((ext_vector_type(4))) float;
using s16x8 = __attribute__((ext_vector_type(8))) short;

static __device__ __forceinline__ unsigned short bf16_rne(float f) {
    union { float f; unsigned u; } v; v.f = f;
    unsigned u = v.u;
    unsigned r = (u + 0x7fffu + ((u >> 16) & 1u)) >> 16;
    return (unsigned short)r;
}

// async global -> LDS, 16 B per lane, wave-uniform LDS base (m97/m104 pattern)
#define GLOAD_LDS16(gp, lp)                                                    \
    __builtin_amdgcn_global_load_lds(                                          \
        (const __attribute__((address_space(1))) void*)(gp),                   \
        (__attribute__((address_space(3))) void*)(lp), 16, 0, 0)

// ---------------- X f32 -> bf16 elementwise (grid-stride, vectorized)
__global__ void cvt_x(const float* __restrict__ src, unsigned short* __restrict__ dst,
                      long total4) {
    long i0 = blockIdx.x * 256 + threadIdx.x;
    long stride = (long)gridDim.x * 256;
    for (long i = i0; i < total4; i += stride) {
        f32x4 v = *(const f32x4*)&src[i * 4];
        uint2 w;
        w.x = (unsigned)bf16_rne(v[0]) | ((unsigned)bf16_rne(v[1]) << 16);
        w.y = (unsigned)bf16_rne(v[2]) | ((unsigned)bf16_rne(v[3]) << 16);
        *(uint2*)&dst[i * 4] = w;
    }
}

// ---------------- transpose + f32->bf16: src[R][C] f32 -> dst[C][R] bf16
__global__ void transpose_cvt(const float* __restrict__ src, unsigned short* __restrict__ dst,
                              int R, int C) {
    __shared__ unsigned short tile[32][33];
    int c0 = blockIdx.x * 32, r0 = blockIdx.y * 32;
    int tx = threadIdx.x, ty = threadIdx.y;  // 32 x 8
#pragma unroll
    for (int i = ty; i < 32; i += 8)
        tile[i][tx] = bf16_rne(src[(size_t)(r0 + i) * C + c0 + tx]);
    __syncthreads();
#pragma unroll
    for (int i = ty; i < 32; i += 8)
        dst[(size_t)(c0 + i) * R + r0 + tx] = tile[tx][i];
}

// ---------------- graph build
__global__ void zero_deg(int* deg) { deg[blockIdx.x * 256 + threadIdx.x] = 0; }

__global__ void count_deg(const int* __restrict__ dst, int* deg) {
    int e = blockIdx.x * 256 + threadIdx.x;
    atomicAdd(&deg[dst[e]], 1);
}

__global__ void scan_kernel(const int* __restrict__ deg, int* __restrict__ off,
                            int* __restrict__ cursor, float* __restrict__ dinv) {
    __shared__ int buf[2][N_NODES];
    int t = threadIdx.x;  // 1024
    for (int i = t; i < N_NODES; i += 1024) buf[0][i] = deg[i];
    __syncthreads();
    int cur = 0;
    for (int s = 1; s < N_NODES; s <<= 1) {
        for (int i = t; i < N_NODES; i += 1024) {
            int v = buf[cur][i];
            if (i >= s) v += buf[cur][i - s];
            buf[cur ^ 1][i] = v;
        }
        __syncthreads();
        cur ^= 1;
    }
    for (int i = t; i < N_NODES; i += 1024) {
        int ex = i ? buf[cur][i - 1] : 0;
        off[i] = ex;
        cursor[i] = ex;
        dinv[i] = rsqrtf((float)(deg[i] + 1));  // +1 = self-loop
    }
    if (t == 0) off[N_NODES] = buf[cur][N_NODES - 1];
}

__global__ void scatter_edges(const int* __restrict__ src, const int* __restrict__ dst,
                              int* cursor, int* csr) {
    int e = blockIdx.x * 256 + threadIdx.x;
    int d = dst[e];
    int slot = atomicAdd(&cursor[d], 1);
    csr[slot] = src[e];
}

// ---------------- fast GEMM (m97 structure): bf16 A [M][lda] x bf16 BT [N][ldbt]^T
// global_load_lds staging, linear LDS, 128x128x64 tile, 4 waves, 16x16x32 MFMA.
__global__ __launch_bounds__(256) void gemm_lds(
    const unsigned short* __restrict__ A, const unsigned short* __restrict__ BT,
    float* __restrict__ Cpart, int M, int N, int lda, int ldbt, int k_chunk) {
    constexpr int BM = 128, BN = 128, BK = 64;
    __shared__ unsigned short lsA[BM * BK];
    __shared__ unsigned short lsB[BN * BK];

    const int tid = threadIdx.x;
    const int bm0 = blockIdx.x * BM;
    const int bn0 = blockIdx.y * BN;
    const int k0base = blockIdx.z * k_chunk;
    float* C = Cpart + (size_t)blockIdx.z * M * N;

    const int w = tid >> 6, lane = tid & 63;
    const int l15 = lane & 15, lh = lane >> 4;
    const int lrow = lane >> 3;          // 0..7 row within 8-row segment
    const int lcol = (lane & 7) * 8;     // 0..56 bf16 col

    f32x4 acc[4][4] = {};

    const int nsteps = k_chunk / BK;
    for (int s = 0; s < nsteps; ++s) {
        const int k0 = k0base + s * BK;
        // stage A tile [BM][BK]: 4 instrs x 4 waves x 8 rows x 64 cols
#pragma unroll
        for (int i = 0; i < 4; ++i) {
            int r = i * 32 + w * 8;
            GLOAD_LDS16(&A[(size_t)(bm0 + r + lrow) * lda + k0 + lcol],
                        &lsA[r * BK]);
        }
#pragma unroll
        for (int i = 0; i < 4; ++i) {
            int r = i * 32 + w * 8;
            GLOAD_LDS16(&BT[(size_t)(bn0 + r + lrow) * ldbt + k0 + lcol],
                        &lsB[r * BK]);
        }
        __syncthreads();  // drains vmcnt before LDS reads
        const int wr = (w >> 1) * 64, wc = (w & 1) * 64;
#pragma unroll
        for (int kk = 0; kk < BK; kk += 32) {
            s16x8 af[4], bf[4];
#pragma unroll
            for (int mi = 0; mi < 4; ++mi)
                af[mi] = *(const s16x8*)&lsA[(wr + mi * 16 + l15) * BK + kk + lh * 8];
#pragma unroll
            for (int ni = 0; ni < 4; ++ni)
                bf[ni] = *(const s16x8*)&lsB[(wc + ni * 16 + l15) * BK + kk + lh * 8];
#pragma unroll
            for (int mi = 0; mi < 4; ++mi)
#pragma unroll
                for (int ni = 0; ni < 4; ++ni)
                    acc[mi][ni] = __builtin_amdgcn_mfma_f32_16x16x32_bf16(
                        af[mi], bf[ni], acc[mi][ni], 0, 0, 0);
        }
        __syncthreads();
    }
    // epilogue: D row=(lane>>4)*4+reg, col=lane&15 (m89-verified)
    const int wr = (w >> 1) * 64, wc = (w & 1) * 64;
#pragma unroll
    for (int mi = 0; mi < 4; ++mi)
#pragma unroll
        for (int ni = 0; ni < 4; ++ni)
#pragma unroll
            for (int r = 0; r < 4; ++r) {
                int row = bm0 + wr + mi * 16 + lh * 4 + r;
                int col = bn0 + wc + ni * 16 + l15;
                C[(size_t)row * N + col] = acc[mi][ni][r];
            }
}

// ---------------- fallback GEMM (round-0): f32 A reg-staged + cvt, padded LDS
__global__ __launch_bounds__(256) void gemm_a32(
    const float* __restrict__ A, const unsigned short* __restrict__ BT,
    float* __restrict__ Cpart, int M, int N, int lda, int ldbt, int k_chunk) {
    constexpr int BM = 128, BN = 128, BK = 64;
    constexpr int LDP = 72;
    __shared__ unsigned short lsA[BM * LDP];
    __shared__ unsigned short lsB[BN * LDP];

    const int tid = threadIdx.x;
    const int bm0 = blockIdx.x * BM;
    const int bn0 = blockIdx.y * BN;
    const int k0base = blockIdx.z * k_chunk;
    float* C = Cpart + (size_t)blockIdx.z * M * N;

    const int wid = tid >> 6, lane = tid & 63;
    const int wr = (wid >> 1) * 64, wc = (wid & 1) * 64;
    const int l15 = lane & 15, lh = lane >> 4;

    f32x4 acc[4][4] = {};

    const int nsteps = k_chunk / BK;
    for (int s = 0; s < nsteps; ++s) {
        const int k0 = k0base + s * BK;
#pragma unroll
        for (int i = 0; i < 8; ++i) {
            int r = (tid >> 4) + i * 16;
            int c = (tid & 15) * 4;
            f32x4 v = *(const f32x4*)&A[(size_t)(bm0 + r) * lda + k0 + c];
            uint2 wv;
            wv.x = (unsigned)bf16_rne(v[0]) | ((unsigned)bf16_rne(v[1]) << 16);
            wv.y = (unsigned)bf16_rne(v[2]) | ((unsigned)bf16_rne(v[3]) << 16);
            *(uint2*)&lsA[r * LDP + c] = wv;
        }
#pragma unroll
        for (int i = 0; i < 4; ++i) {
            int r = (tid >> 3) + i * 32;
            int c = (tid & 7) * 8;
            *(f32x4*)&lsB[r * LDP + c] = *(const f32x4*)&BT[(size_t)(bn0 + r) * ldbt + k0 + c];
        }
        __syncthreads();
#pragma unroll
        for (int kk = 0; kk < BK; kk += 32) {
            s16x8 af[4], bf[4];
#pragma unroll
            for (int mi = 0; mi < 4; ++mi)
                af[mi] = *(const s16x8*)&lsA[(wr + mi * 16 + l15) * LDP + kk + lh * 8];
#pragma unroll
            for (int ni = 0; ni < 4; ++ni)
                bf[ni] = *(const s16x8*)&lsB[(wc + ni * 16 + l15) * LDP + kk + lh * 8];
#pragma unroll
            for (int mi = 0; mi < 4; ++mi)
#pragma unroll
                for (int ni = 0; ni < 4; ++ni)
                    acc[mi][ni] = __builtin_amdgcn_mfma_f32_16x16x32_bf16(
                        af[mi], bf[ni], acc[mi][ni], 0, 0, 0);
        }
        __syncthreads();
    }
#pragma unroll
    for (int mi = 0; mi < 4; ++mi)
#pragma unroll
        for (int ni = 0; ni < 4; ++ni)
#pragma unroll
            for (int r = 0; r < 4; ++r) {
                int row = bm0 + wr + mi * 16 + lh * 4 + r;
                int col = bn0 + wc + ni * 16 + l15;
                C[(size_t)row * N + col] = acc[mi][ni][r];
            }
}

// ---------------- split-K reduce: O = sum_p P[p]
__global__ void reduce_k(const float* __restrict__ P, float* __restrict__ O, int MN, int parts) {
    int i = (blockIdx.x * 256 + threadIdx.x) * 4;
    f32x4 s = *(const f32x4*)&P[i];
    for (int p = 1; p < parts; ++p) s += *(const f32x4*)&P[(size_t)p * MN + i];
    *(f32x4*)&O[i] = s;
}

// ---------------- propagation layer 1 -> bf16 relu
__global__ void prop1_k(const float* __restrict__ H, const int* __restrict__ off,
                        const int* __restrict__ csr, const float* __restrict__ dinv,
                        const float* __restrict__ b, unsigned short* __restrict__ Abf) {
    int n = blockIdx.x;
    int f = threadIdx.x * 4;  // 256 * 4 = 1024
    int e0 = off[n], e1 = off[n + 1];
    float dn = dinv[n];
    f32x4 a = {0.f, 0.f, 0.f, 0.f};
    for (int e = e0; e < e1; ++e) {
        int s = csr[e];
        a += dinv[s] * *(const f32x4*)&H[(size_t)s * F_H + f];
    }
    f32x4 hn = *(const f32x4*)&H[(size_t)n * F_H + f];
    f32x4 bb = *(const f32x4*)&b[f];
    f32x4 o = dn * a + (dn * dn) * hn + bb;
    unsigned short r[4];
#pragma unroll
    for (int j = 0; j < 4; ++j) {
        float x = o[j] > 0.f ? o[j] : 0.f;
        r[j] = bf16_rne(x);
    }
    uint2 w;
    w.x = (unsigned)r[0] | ((unsigned)r[1] << 16);
    w.y = (unsigned)r[2] | ((unsigned)r[3] << 16);
    *(uint2*)&Abf[(size_t)n * F_H + f] = w;
}

// ---------------- propagation layer 2 -> f32 relu
__global__ void prop2_k(const float* __restrict__ H, const int* __restrict__ off,
                        const int* __restrict__ csr, const float* __restrict__ dinv,
                        const float* __restrict__ b, float* __restrict__ A2) {
    int n = blockIdx.x;
    int f = threadIdx.x * 4;  // 64 * 4 = 256
    int e0 = off[n], e1 = off[n + 1];
    float dn = dinv[n];
    f32x4 a = {0.f, 0.f, 0.f, 0.f};
    for (int e = e0; e < e1; ++e) {
        int s = csr[e];
        a += dinv[s] * *(const f32x4*)&H[(size_t)s * F_H2 + f];
    }
    f32x4 hn = *(const f32x4*)&H[(size_t)n * F_H2 + f];
    f32x4 bb = *(const f32x4*)&b[f];
    f32x4 o = dn * a + (dn * dn) * hn + bb;
#pragma unroll
    for (int j = 0; j < 4; ++j) o[j] = o[j] > 0.f ? o[j] : 0.f;
    *(f32x4*)&A2[(size_t)n * F_H2 + f] = o;
}

// ---------------- pooling partials
__global__ void pool_partial(const float* __restrict__ A2, float* __restrict__ pp) {
    int b = blockIdx.x, t = threadIdx.x;  // 32 blocks, 256 threads
    float s = 0.f;
    for (int i = 0; i < 64; ++i) s += A2[(size_t)(b * 64 + i) * F_H2 + t];
    pp[b * F_H2 + t] = s;
}

// ---------------- final: mean, fc, log_softmax
__global__ void final_k(const float* __restrict__ pp, const float* __restrict__ fcW,
                        const float* __restrict__ fcb, float* __restrict__ out) {
    __shared__ float r0[256], r1[256];
    int t = threadIdx.x;
    float s = 0.f;
    for (int b = 0; b < 32; ++b) s += pp[b * 256 + t];
    float g = s * (1.f / 2048.f);
    r0[t] = g * fcW[t * 2 + 0];
    r1[t] = g * fcW[t * 2 + 1];
    __syncthreads();
    for (int h = 128; h > 0; h >>= 1) {
        if (t < h) { r0[t] += r0[t + h]; r1[t] += r1[t + h]; }
        __syncthreads();
    }
    if (t == 0) {
        float l0 = r0[0] + fcb[0], l1 = r1[0] + fcb[1];
        float m = fmaxf(l0, l1);
        float lse = m + logf(expf(l0 - m) + expf(l1 - m));
        out[0] = l0 - lse;
        out[1] = l1 - lse;
    }
}

extern "C" void kernel_launch(void* const* d_in, const int* in_sizes, int n_in,
                              void* d_out, int out_size, void* d_ws, size_t ws_size,
                              hipStream_t stream) {
    const float* x   = (const float*)d_in[0];
    const int*   ei  = (const int*)d_in[1];  // [2][32768]: row0=src, row1=dst
    const float* W1  = (const float*)d_in[2];
    const float* b1  = (const float*)d_in[3];
    const float* W2  = (const float*)d_in[4];
    const float* b2  = (const float*)d_in[5];
    const float* fcW = (const float*)d_in[6];
    const float* fcb = (const float*)d_in[7];
    float* out = (float*)d_out;

    char* ws = (char*)d_ws;
    size_t o = 0;
    auto alloc = [&](size_t bytes) { void* p = ws + o; o += (bytes + 255) & ~(size_t)255; return p; };

    // common buffers
    unsigned short* W1T = (unsigned short*)alloc((size_t)F_H * F_IN * 2);      // 102.8 MB
    unsigned short* W2T = (unsigned short*)alloc((size_t)F_H2 * F_H * 2);      // 0.5 MB
    float* H1  = (float*)alloc((size_t)N_NODES * F_H * 4);                     // 8.4 MB
    unsigned short* A1 = (unsigned short*)alloc((size_t)N_NODES * F_H * 2);    // 4.2 MB
    float* H2p = (float*)alloc((size_t)SK2 * N_NODES * F_H2 * 4);              // 16.8 MB
    float* H2  = (float*)alloc((size_t)N_NODES * F_H2 * 4);                    // 2.1 MB
    float* A2  = (float*)alloc((size_t)N_NODES * F_H2 * 4);                    // 2.1 MB
    float* pp  = (float*)alloc(32 * F_H2 * 4);
    int* deg    = (int*)alloc(N_NODES * 4);
    int* off    = (int*)alloc((N_NODES + 1) * 4);
    int* cursor = (int*)alloc(N_NODES * 4);
    float* dinv = (float*)alloc(N_NODES * 4);
    int* csr    = (int*)alloc(N_EDGES * 4);
    size_t o_common = o;

    // fast-path buffers
    size_t xbf_b = (size_t)N_NODES * F_IN * 2;        // 205.5 MB
    size_t hp8_b = (size_t)FSK1 * N_NODES * F_H * 4;  // 67.1 MB
    bool fast = (o_common + ((xbf_b + 255) & ~(size_t)255)
                          + ((hp8_b + 255) & ~(size_t)255)) <= ws_size;

    // weight prep
    transpose_cvt<<<dim3(F_H / 32, F_IN / 32), dim3(32, 8), 0, stream>>>(W1, W1T, F_IN, F_H);
    transpose_cvt<<<dim3(F_H2 / 32, F_H / 32), dim3(32, 8), 0, stream>>>(W2, W2T, F_H, F_H2);

    // CSR build
    zero_deg<<<N_NODES / 256, 256, 0, stream>>>(deg);
    count_deg<<<N_EDGES / 256, 256, 0, stream>>>(ei + N_EDGES, deg);
    scan_kernel<<<1, 1024, 0, stream>>>(deg, off, cursor, dinv);
    scatter_edges<<<N_EDGES / 256, 256, 0, stream>>>(ei, ei + N_EDGES, cursor, csr);

    // layer 1: H1 = X @ W1
    if (fast) {
        unsigned short* Xbf = (unsigned short*)alloc(xbf_b);
        float* Hp = (float*)alloc(hp8_b);
        cvt_x<<<2048, 256, 0, stream>>>(x, Xbf, (long)N_NODES * F_IN / 4);
        gemm_lds<<<dim3(16, 8, FSK1), 256, 0, stream>>>(
            Xbf, W1T, Hp, N_NODES, F_H, F_IN, F_IN, F_IN / FSK1);
        reduce_k<<<(N_NODES * F_H / 4) / 256, 256, 0, stream>>>(Hp, H1, N_NODES * F_H, FSK1);
    } else {
        float* Hp = (float*)alloc((size_t)FBK1 * N_NODES * F_H * 4);
        gemm_a32<<<dim3(16, 8, FBK1), 256, 0, stream>>>(
            x, W1T, Hp, N_NODES, F_H, F_IN, F_IN, F_IN / FBK1);
        reduce_k<<<(N_NODES * F_H / 4) / 256, 256, 0, stream>>>(Hp, H1, N_NODES * F_H, FBK1);
    }
    prop1_k<<<N_NODES, 256, 0, stream>>>(H1, off, csr, dinv, b1, A1);

    // layer 2: H2 = A1 @ W2 (bf16 x bf16, global_load_lds path)
    gemm_lds<<<dim3(16, 2, SK2), 256, 0, stream>>>(
        A1, W2T, H2p, N_NODES, F_H2, F_H, F_H, F_H / SK2);
    reduce_k<<<(N_NODES * F_H2 / 4) / 256, 256, 0, stream>>>(H2p, H2, N_NODES * F_H2, SK2);
    prop2_k<<<N_NODES, 64, 0, stream>>>(H2, off, csr, dinv, b2, A2);

    // pool + fc + log_softmax
    pool_partial<<<32, 256, 0, stream>>>(A2, pp);
    final_k<<<1, 256, 0, stream>>>(pp, fcW, fcb, out);
}